// Round 5
// baseline (94.112 us; speedup 1.0000x reference)
//
#include <hip/hip_runtime.h>

#define N_NODES 16384
#define NE 524288
#define WORDS 512          // bitmask words per node row
#define KDIM 1152          // IN*NG + IN
#define KSTEPS 36          // 1152 / 32
#define NBUCK 512          // buckets of 32 nodes
#define BCAP 24            // per-(sortblock,bucket) slot capacity (Poisson mean 4)
#define REGW (NBUCK * BCAP) // words per sort-block region = 12288
#define MROW 516           // padded LDS row stride (words) to break bank conflicts
#define SENTINEL 0xFFFFFFFFu

typedef unsigned int uint32;
typedef unsigned short ushort;
typedef __attribute__((ext_vector_type(8))) short bf16x8;
typedef __attribute__((ext_vector_type(4))) float f32x4;

__device__ __forceinline__ ushort f2bf(float f) {
    unsigned u = __float_as_uint(f);
    unsigned r = (u + 0x7fffu + ((u >> 16) & 1u)) >> 16;
    return (ushort)r;
}
__device__ __forceinline__ float bflo(uint32 u) {
    return __uint_as_float(u << 16);
}
__device__ __forceinline__ float bfhi(uint32 u) {
    return __uint_as_float(u & 0xffff0000u);
}

// ---------------- weight pack into MFMA B-fragment order (bf16) ----------------
__global__ __launch_bounds__(256) void transw_kernel(
    const float* __restrict__ sw, const float* __restrict__ bw,
    ushort* __restrict__ Wp) {
    int idx = blockIdx.x * 256 + threadIdx.x;      // 0 .. 147455
    int i  = idx & 7;
    int l  = (idx >> 3) & 63;
    int ct = (idx >> 9) & 7;
    int kk = idx >> 12;
    int k   = kk * 32 + ((l >> 4) << 3) + i;
    int col = ct * 16 + (l & 15);
    float v = (k < 1024) ? sw[col * 1024 + k] : bw[col * 128 + (k - 1024)];
    Wp[idx] = f2bf(v);
}

// ---------------- LDS-staged binning: private region per block, coalesced flush ----------------
// 512 blocks x 256 threads x 4 edges (8 directed entries) each
__global__ __launch_bounds__(256) void sort_kernel(
    const int* __restrict__ ei, uint32* __restrict__ ebuf) {
    __shared__ uint32 st[REGW];                    // 49152 B, sentinel-padded
    __shared__ int lcnt[NBUCK];
    const int t = threadIdx.x;
    for (int idx = t; idx < REGW; idx += 256) st[idx] = SENTINEL;
    lcnt[t] = 0;
    lcnt[t + 256] = 0;
    __syncthreads();

#pragma unroll
    for (int k = 0; k < 4; ++k) {
        int e = blockIdx.x * 1024 + k * 256 + t;
        int a = ei[e];
        int b = ei[NE + e];
        int ba = a >> 5;
        uint32 pa = ((uint32)(a & 31) << 14) | (uint32)b;
        int pos = atomicAdd(&lcnt[ba], 1);
        if (pos < BCAP) st[ba * BCAP + pos] = pa;
        int bb = b >> 5;
        uint32 pb = ((uint32)(b & 31) << 14) | (uint32)a;
        pos = atomicAdd(&lcnt[bb], 1);
        if (pos < BCAP) st[bb * BCAP + pos] = pb;
    }
    __syncthreads();

    uint32* gout = ebuf + (size_t)blockIdx.x * REGW;
    for (int idx = t; idx < REGW; idx += 256) gout[idx] = st[idx];
}

// ---------------- per-bucket LDS bitmask: dedup degree + full bitmask dump ----------------
// 512 blocks (one per 32-node bucket) x 256 threads
__global__ __launch_bounds__(256) void degb_kernel(
    const uint32* __restrict__ ebuf, float* __restrict__ dis,
    uint32* __restrict__ bm) {
    __shared__ uint32 mask[32 * MROW];              // 66,048 B
    const int t = threadIdx.x;
    const int bkt = blockIdx.x;
    for (int i = t; i < 32 * MROW; i += 256) mask[i] = 0;
    __syncthreads();

    // read this bucket's column across all 512 sort-block regions
    for (int idx = t; idx < 512 * BCAP; idx += 256) {
        int b = idx / BCAP;
        int s = idx - b * BCAP;
        uint32 e = ebuf[(size_t)b * REGW + bkt * BCAP + s];
        if (e < (1u << 19)) {
            int ln = e >> 14;
            int nb = e & 16383;
            atomicOr(&mask[ln * MROW + (nb >> 5)], 1u << (nb & 31));
        }
    }
    __syncthreads();

    // dedup'd degree: 8 threads per node, 2-way-max LDS banks
    {
        const int node = t >> 3;
        const int sub = t & 7;
        const uint32* row = &mask[node * MROW];
        int c = 0;
#pragma unroll
        for (int k = 0; k < 64; ++k) c += __popc(row[sub + k * 8]);
#pragma unroll
        for (int o = 1; o < 8; o <<= 1) c += __shfl_xor(c, o);
        if (sub == 0) dis[bkt * 32 + node] = rsqrtf((float)c);
    }

    // coalesced dump (full overwrite -> no global clear ever needed)
    uint32* gout = bm + (size_t)bkt * 32 * WORDS;
#pragma unroll 4
    for (int k = 0; k < 64; ++k) {
        int g = t + k * 256;
        gout[g] = mask[(g >> 9) * MROW + (g & 511)];
    }
}

// ---------------- fused FastKAN support (bf16 MFMA), pre-scaled by dis ----------------
__global__ __launch_bounds__(256) void support_kernel(
    const float* __restrict__ x, const float* __restrict__ gamma,
    const float* __restrict__ beta, const ushort* __restrict__ Wp,
    const float* __restrict__ base_b, const float* __restrict__ dis,
    ushort* __restrict__ Ssc) {
    __shared__ ushort Bs[16][KDIM];                 // 36864 B
    const int t = threadIdx.x;
    const int lane = t & 63;
    const int w = t >> 6;
    const int nodeBase = blockIdx.x * 16;

    const float g0 = gamma[lane], g1 = gamma[lane + 64];
    const float be0 = beta[lane], be1 = beta[lane + 64];

    for (int n = w * 4; n < w * 4 + 4; ++n) {
        const int row = nodeBase + n;
        float f0 = x[(size_t)row * 128 + lane];
        float f1 = x[(size_t)row * 128 + lane + 64];
        float s = f0 + f1;
#pragma unroll
        for (int o = 32; o; o >>= 1) s += __shfl_xor(s, o);
        float mu = s * 0.0078125f;
        float d0 = f0 - mu, d1 = f1 - mu;
        float v = d0 * d0 + d1 * d1;
#pragma unroll
        for (int o = 32; o; o >>= 1) v += __shfl_xor(v, o);
        float rstd = rsqrtf(v * 0.0078125f + 1e-5f);
        float h0 = d0 * rstd * g0 + be0;
        float h1 = d1 * rstd * g1 + be1;
        ushort pk0[8] __attribute__((aligned(16)));
        ushort pk1[8] __attribute__((aligned(16)));
#pragma unroll
        for (int g = 0; g < 8; ++g) {
            float gv = -2.0f + (float)g * (4.0f / 7.0f);
            float z0 = (h0 - gv) * 1.75f;
            float z1 = (h1 - gv) * 1.75f;
            pk0[g] = f2bf(__expf(-z0 * z0));
            pk1[g] = f2bf(__expf(-z1 * z1));
        }
        *reinterpret_cast<uint4*>(&Bs[n][lane * 8]) =
            *reinterpret_cast<const uint4*>(pk0);
        *reinterpret_cast<uint4*>(&Bs[n][(lane + 64) * 8]) =
            *reinterpret_cast<const uint4*>(pk1);
        Bs[n][1024 + lane]      = f2bf(f0 / (1.0f + __expf(-f0)));
        Bs[n][1024 + lane + 64] = f2bf(f1 / (1.0f + __expf(-f1)));
    }
    __syncthreads();

    const int ct0 = w * 2;
    f32x4 acc0 = {0.f, 0.f, 0.f, 0.f};
    f32x4 acc1 = {0.f, 0.f, 0.f, 0.f};
    const ushort* ArowBase = &Bs[lane & 15][(lane >> 4) * 8];
    const bf16x8* Wv = (const bf16x8*)Wp;
#pragma unroll 4
    for (int kk = 0; kk < KSTEPS; ++kk) {
        bf16x8 a = *reinterpret_cast<const bf16x8*>(ArowBase + kk * 32);
        bf16x8 b0 = Wv[(size_t)(kk * 8 + ct0) * 64 + lane];
        bf16x8 b1 = Wv[(size_t)(kk * 8 + ct0 + 1) * 64 + lane];
        acc0 = __builtin_amdgcn_mfma_f32_16x16x32_bf16(a, b0, acc0, 0, 0, 0);
        acc1 = __builtin_amdgcn_mfma_f32_16x16x32_bf16(a, b1, acc1, 0, 0, 0);
    }

    const int col0 = ct0 * 16 + (lane & 15);
    const int rbase = (lane >> 4) * 4;
    const float bb0 = base_b[col0];
    const float bb1 = base_b[col0 + 16];
#pragma unroll
    for (int r = 0; r < 4; ++r) {
        const int row = nodeBase + rbase + r;
        const float di = dis[row];
        Ssc[(size_t)row * 128 + col0]      = f2bf((acc0[r] + bb0) * di);
        Ssc[(size_t)row * 128 + col0 + 16] = f2bf((acc1[r] + bb1) * di);
    }
}

// ---------------- aggregation: out[i] = dis_i * sum Ssc[nbr] + bias ----------------
__global__ __launch_bounds__(128) void aggregate_kernel(
    const uint32* __restrict__ bm, const ushort* __restrict__ Ssc,
    const float* __restrict__ dis, const float* __restrict__ bias,
    float* __restrict__ out) {
    __shared__ ushort lst[4096];
    __shared__ int cnts[128];
    __shared__ float part[2][128];
    const int t = threadIdx.x;
    const int i = blockIdx.x;

    uint4 w4 = ((const uint4*)(bm + (size_t)i * WORDS))[t];
    uint32 wsv[4] = {w4.x, w4.y, w4.z, w4.w};
    int myc = __popc(wsv[0]) + __popc(wsv[1]) + __popc(wsv[2]) + __popc(wsv[3]);
    cnts[t] = myc;
    __syncthreads();
#pragma unroll
    for (int off = 1; off < 128; off <<= 1) {
        int v = cnts[t];
        int add = (t >= off) ? cnts[t - off] : 0;
        __syncthreads();
        cnts[t] = v + add;
        __syncthreads();
    }
    int st = cnts[t] - myc;
    int total = cnts[127];
    if (total > 4096) total = 4096;

    int pos = st;
#pragma unroll
    for (int q = 0; q < 4; ++q) {
        uint32 wbits = wsv[q];
        int cbase = t * 128 + q * 32;
        while (wbits) {
            int b = __ffs(wbits) - 1;
            wbits &= wbits - 1;
            if (pos < 4096) lst[pos] = (ushort)(cbase + b);
            ++pos;
        }
    }
    __syncthreads();

    const int lane = t & 63;
    const int wv = t >> 6;
    const uint32* S32 = (const uint32*)Ssc;          // row stride 64 uints
    float a0 = 0.f, a1 = 0.f;
    int idx = wv;
    for (; idx + 6 < total; idx += 8) {
        int j0 = lst[idx], j1 = lst[idx + 2], j2 = lst[idx + 4], j3 = lst[idx + 6];
        uint32 u0 = S32[(size_t)j0 * 64 + lane];
        uint32 u1 = S32[(size_t)j1 * 64 + lane];
        uint32 u2 = S32[(size_t)j2 * 64 + lane];
        uint32 u3 = S32[(size_t)j3 * 64 + lane];
        a0 += (bflo(u0) + bflo(u1)) + (bflo(u2) + bflo(u3));
        a1 += (bfhi(u0) + bfhi(u1)) + (bfhi(u2) + bfhi(u3));
    }
    for (; idx < total; idx += 2) {
        uint32 u = S32[(size_t)lst[idx] * 64 + lane];
        a0 += bflo(u);
        a1 += bfhi(u);
    }
    part[wv][lane * 2]     = a0;
    part[wv][lane * 2 + 1] = a1;
    __syncthreads();

    float v = part[0][t] + part[1][t];
    out[(size_t)i * 128 + t] = v * dis[i] + bias[t];
}

extern "C" void kernel_launch(void* const* d_in, const int* in_sizes, int n_in,
                              void* d_out, int out_size, void* d_ws, size_t ws_size,
                              hipStream_t stream) {
    const float* x        = (const float*)d_in[0];
    const int*   ei       = (const int*)d_in[1];
    const float* ln_gamma = (const float*)d_in[2];
    const float* ln_beta  = (const float*)d_in[3];
    const float* spline_w = (const float*)d_in[4];
    const float* base_w   = (const float*)d_in[5];
    const float* base_b   = (const float*)d_in[6];
    const float* bias     = (const float*)d_in[7];
    float* out = (float*)d_out;

    char* ws = (char*)d_ws;
    const size_t WP_OFF  = 0;              //    294,912 B
    const size_t DIS_OFF = 294912;         //     65,536 B
    const size_t BM_OFF  = 360448;         // 33,554,432 B
    const size_t ES_OFF  = 33914880;       // max(ebuf 25,165,824 ; Ssc 4,194,304)
    const size_t NEEDED  = 59080704;
    if (ws_size < NEEDED) return;

    ushort* Wp   = (ushort*)(ws + WP_OFF);
    float*  dis  = (float*)(ws + DIS_OFF);
    uint32* bm   = (uint32*)(ws + BM_OFF);
    uint32* ebuf = (uint32*)(ws + ES_OFF);         // dead after degb_kernel
    ushort* Ssc  = (ushort*)(ws + ES_OFF);         // written by support afterwards

    transw_kernel<<<576, 256, 0, stream>>>(spline_w, base_w, Wp);
    sort_kernel<<<512, 256, 0, stream>>>(ei, ebuf);
    degb_kernel<<<NBUCK, 256, 0, stream>>>(ebuf, dis, bm);
    support_kernel<<<N_NODES / 16, 256, 0, stream>>>(x, ln_gamma, ln_beta, Wp,
                                                     base_b, dis, Ssc);
    aggregate_kernel<<<N_NODES, 128, 0, stream>>>(bm, Ssc, dis, bias, out);
}

// Round 6
// 90.190 us; speedup vs baseline: 1.0435x; 1.0435x over previous
//
#include <hip/hip_runtime.h>

#define N_NODES 16384
#define NE 524288
#define KDIM 1152          // IN*NG + IN
#define KSTEPS 36          // 1152 / 32
#define NBUCK 512          // buckets of 32 nodes
#define BCAP 2816          // per-bucket entry capacity (mean 2048, +17 sigma)
#define MROW 516           // padded LDS row stride (words) to break bank conflicts
#define DCAP 256           // per-node dedup'd neighbor capacity (mean 64)

typedef unsigned int uint32;
typedef unsigned short ushort;
typedef __attribute__((ext_vector_type(8))) short bf16x8;
typedef __attribute__((ext_vector_type(4))) float f32x4;

__device__ __forceinline__ ushort f2bf(float f) {
    unsigned u = __float_as_uint(f);
    unsigned r = (u + 0x7fffu + ((u >> 16) & 1u)) >> 16;
    return (ushort)r;
}
__device__ __forceinline__ float bflo(uint32 u) {
    return __uint_as_float(u << 16);
}
__device__ __forceinline__ float bfhi(uint32 u) {
    return __uint_as_float(u & 0xffff0000u);
}

// ---------------- weight pack into MFMA B-fragment order + cursor init ----------------
__global__ __launch_bounds__(256) void transw_kernel(
    const float* __restrict__ sw, const float* __restrict__ bw,
    ushort* __restrict__ Wp, int* __restrict__ cursor) {
    int idx = blockIdx.x * 256 + threadIdx.x;      // 0 .. 147455
    if (idx < NBUCK) cursor[idx] = idx * BCAP;
    int i  = idx & 7;
    int l  = (idx >> 3) & 63;
    int ct = (idx >> 9) & 7;
    int kk = idx >> 12;
    int k   = kk * 32 + ((l >> 4) << 3) + i;
    int col = ct * 16 + (l & 15);
    float v = (k < 1024) ? sw[col * 1024 + k] : bw[col * 128 + (k - 1024)];
    Wp[idx] = f2bf(v);
}

// ---------------- bin directed edges into 512 node-range buckets (R4 form) ----------------
__global__ __launch_bounds__(256) void sort_kernel(
    const int* __restrict__ ei, int* __restrict__ cursor,
    uint32* __restrict__ ebuf) {
    __shared__ int hcnt[NBUCK];
    __shared__ int gbase[NBUCK];
    const int t = threadIdx.x;
    hcnt[t] = 0;
    hcnt[t + 256] = 0;
    __syncthreads();

    int bk[8], sl[8];
    uint32 pk[8];
#pragma unroll
    for (int k = 0; k < 4; ++k) {
        int e = blockIdx.x * 1024 + k * 256 + t;
        int a = ei[e];
        int b = ei[NE + e];
        bk[2 * k]     = a >> 5;
        pk[2 * k]     = ((uint32)(a & 31) << 14) | (uint32)b;
        bk[2 * k + 1] = b >> 5;
        pk[2 * k + 1] = ((uint32)(b & 31) << 14) | (uint32)a;
        sl[2 * k]     = atomicAdd(&hcnt[bk[2 * k]], 1);
        sl[2 * k + 1] = atomicAdd(&hcnt[bk[2 * k + 1]], 1);
    }
    __syncthreads();
    for (int q = t; q < NBUCK; q += 256) {
        int c = hcnt[q];
        gbase[q] = c ? atomicAdd(cursor + q, c) : 0;
    }
    __syncthreads();
#pragma unroll
    for (int k = 0; k < 8; ++k) {
        int idx = gbase[bk[k]] + sl[k];
        if (idx < (bk[k] + 1) * BCAP)
            ebuf[idx] = pk[k];
    }
}

// ---------------- per-bucket LDS bitmask -> dedup'd CSR (deg, dis, dadj) ----------------
// 512 blocks (one per 32-node bucket) x 256 threads (4 waves x 8 nodes each)
__global__ __launch_bounds__(256) void degb_kernel(
    const int* __restrict__ cursor, const uint32* __restrict__ ebuf,
    float* __restrict__ dis, int* __restrict__ degarr,
    ushort* __restrict__ dadj) {
    __shared__ uint32 mask[32 * MROW];              // 66,048 B
    const int t = threadIdx.x;
    const int bkt = blockIdx.x;
    for (int i = t; i < 32 * MROW; i += 256) mask[i] = 0;
    __syncthreads();

    int cnt = cursor[bkt] - bkt * BCAP;
    if (cnt > BCAP) cnt = BCAP;
    const uint32* eb = ebuf + (size_t)bkt * BCAP;
    for (int p = t; p < cnt; p += 256) {
        uint32 e = eb[p];
        int ln = e >> 14;
        int nb = e & 16383;
        atomicOr(&mask[ln * MROW + (nb >> 5)], 1u << (nb & 31));
    }
    __syncthreads();

    // compaction: wave w handles nodes w*8 .. w*8+7; lane owns words lane+64j
    const int lane = t & 63;
    const int w = t >> 6;
    for (int n = w * 8; n < w * 8 + 8; ++n) {
        const uint32* row = &mask[n * MROW];
        uint32 wd[8];
        int c = 0;
#pragma unroll
        for (int j = 0; j < 8; ++j) {
            wd[j] = row[lane + 64 * j];
            c += __popc(wd[j]);
        }
        int inc = c;
#pragma unroll
        for (int o = 1; o < 64; o <<= 1) {
            int v = __shfl_up(inc, o);
            if (lane >= o) inc += v;
        }
        int total = __shfl(inc, 63);
        int pos = inc - c;                          // exclusive base for this lane
        const int node = bkt * 32 + n;
        if (lane == 0) {
            dis[node] = rsqrtf((float)total);
            degarr[node] = total > DCAP ? DCAP : total;
        }
        ushort* drow = dadj + (size_t)node * DCAP;
#pragma unroll
        for (int j = 0; j < 8; ++j) {
            uint32 bits = wd[j];
            int base = (lane + 64 * j) * 32;
            while (bits) {
                int b = __ffs(bits) - 1;
                bits &= bits - 1;
                if (pos < DCAP) drow[pos] = (ushort)(base + b);
                ++pos;
            }
        }
    }
}

// ---------------- fused FastKAN support (bf16 MFMA), pre-scaled by dis ----------------
__global__ __launch_bounds__(256) void support_kernel(
    const float* __restrict__ x, const float* __restrict__ gamma,
    const float* __restrict__ beta, const ushort* __restrict__ Wp,
    const float* __restrict__ base_b, const float* __restrict__ dis,
    ushort* __restrict__ Ssc) {
    __shared__ ushort Bs[16][KDIM];                 // 36864 B
    const int t = threadIdx.x;
    const int lane = t & 63;
    const int w = t >> 6;
    const int nodeBase = blockIdx.x * 16;

    const float g0 = gamma[lane], g1 = gamma[lane + 64];
    const float be0 = beta[lane], be1 = beta[lane + 64];

    for (int n = w * 4; n < w * 4 + 4; ++n) {
        const int row = nodeBase + n;
        float f0 = x[(size_t)row * 128 + lane];
        float f1 = x[(size_t)row * 128 + lane + 64];
        float s = f0 + f1;
#pragma unroll
        for (int o = 32; o; o >>= 1) s += __shfl_xor(s, o);
        float mu = s * 0.0078125f;
        float d0 = f0 - mu, d1 = f1 - mu;
        float v = d0 * d0 + d1 * d1;
#pragma unroll
        for (int o = 32; o; o >>= 1) v += __shfl_xor(v, o);
        float rstd = rsqrtf(v * 0.0078125f + 1e-5f);
        float h0 = d0 * rstd * g0 + be0;
        float h1 = d1 * rstd * g1 + be1;
        ushort pk0[8] __attribute__((aligned(16)));
        ushort pk1[8] __attribute__((aligned(16)));
#pragma unroll
        for (int g = 0; g < 8; ++g) {
            float gv = -2.0f + (float)g * (4.0f / 7.0f);
            float z0 = (h0 - gv) * 1.75f;
            float z1 = (h1 - gv) * 1.75f;
            pk0[g] = f2bf(__expf(-z0 * z0));
            pk1[g] = f2bf(__expf(-z1 * z1));
        }
        *reinterpret_cast<uint4*>(&Bs[n][lane * 8]) =
            *reinterpret_cast<const uint4*>(pk0);
        *reinterpret_cast<uint4*>(&Bs[n][(lane + 64) * 8]) =
            *reinterpret_cast<const uint4*>(pk1);
        Bs[n][1024 + lane]      = f2bf(f0 / (1.0f + __expf(-f0)));
        Bs[n][1024 + lane + 64] = f2bf(f1 / (1.0f + __expf(-f1)));
    }
    __syncthreads();

    const int ct0 = w * 2;
    f32x4 acc0 = {0.f, 0.f, 0.f, 0.f};
    f32x4 acc1 = {0.f, 0.f, 0.f, 0.f};
    const ushort* ArowBase = &Bs[lane & 15][(lane >> 4) * 8];
    const bf16x8* Wv = (const bf16x8*)Wp;
#pragma unroll 4
    for (int kk = 0; kk < KSTEPS; ++kk) {
        bf16x8 a = *reinterpret_cast<const bf16x8*>(ArowBase + kk * 32);
        bf16x8 b0 = Wv[(size_t)(kk * 8 + ct0) * 64 + lane];
        bf16x8 b1 = Wv[(size_t)(kk * 8 + ct0 + 1) * 64 + lane];
        acc0 = __builtin_amdgcn_mfma_f32_16x16x32_bf16(a, b0, acc0, 0, 0, 0);
        acc1 = __builtin_amdgcn_mfma_f32_16x16x32_bf16(a, b1, acc1, 0, 0, 0);
    }

    const int col0 = ct0 * 16 + (lane & 15);
    const int rbase = (lane >> 4) * 4;
    const float bb0 = base_b[col0];
    const float bb1 = base_b[col0 + 16];
#pragma unroll
    for (int r = 0; r < 4; ++r) {
        const int row = nodeBase + rbase + r;
        const float di = dis[row];
        Ssc[(size_t)row * 128 + col0]      = f2bf((acc0[r] + bb0) * di);
        Ssc[(size_t)row * 128 + col0 + 16] = f2bf((acc1[r] + bb1) * di);
    }
}

// ---------------- aggregation from dedup'd CSR ----------------
__global__ __launch_bounds__(128) void aggregate_kernel(
    const int* __restrict__ degarr, const ushort* __restrict__ dadj,
    const ushort* __restrict__ Ssc, const float* __restrict__ dis,
    const float* __restrict__ bias, float* __restrict__ out) {
    __shared__ ushort lst[DCAP];
    __shared__ float part[2][128];
    const int t = threadIdx.x;
    const int i = blockIdx.x;

    const int total = degarr[i];
    const ushort* drow = dadj + (size_t)i * DCAP;
    if (t < total) lst[t] = drow[t];
    if (t + 128 < total) lst[t + 128] = drow[t + 128];
    __syncthreads();

    const int lane = t & 63;
    const int wv = t >> 6;
    const uint32* S32 = (const uint32*)Ssc;          // row stride 64 uints
    float a0 = 0.f, a1 = 0.f;
    int idx = wv;
    for (; idx + 6 < total; idx += 8) {
        int j0 = lst[idx], j1 = lst[idx + 2], j2 = lst[idx + 4], j3 = lst[idx + 6];
        uint32 u0 = S32[(size_t)j0 * 64 + lane];
        uint32 u1 = S32[(size_t)j1 * 64 + lane];
        uint32 u2 = S32[(size_t)j2 * 64 + lane];
        uint32 u3 = S32[(size_t)j3 * 64 + lane];
        a0 += (bflo(u0) + bflo(u1)) + (bflo(u2) + bflo(u3));
        a1 += (bfhi(u0) + bfhi(u1)) + (bfhi(u2) + bfhi(u3));
    }
    for (; idx < total; idx += 2) {
        uint32 u = S32[(size_t)lst[idx] * 64 + lane];
        a0 += bflo(u);
        a1 += bfhi(u);
    }
    part[wv][lane * 2]     = a0;
    part[wv][lane * 2 + 1] = a1;
    __syncthreads();

    float v = part[0][t] + part[1][t];
    out[(size_t)i * 128 + t] = v * dis[i] + bias[t];
}

extern "C" void kernel_launch(void* const* d_in, const int* in_sizes, int n_in,
                              void* d_out, int out_size, void* d_ws, size_t ws_size,
                              hipStream_t stream) {
    const float* x        = (const float*)d_in[0];
    const int*   ei       = (const int*)d_in[1];
    const float* ln_gamma = (const float*)d_in[2];
    const float* ln_beta  = (const float*)d_in[3];
    const float* spline_w = (const float*)d_in[4];
    const float* base_w   = (const float*)d_in[5];
    const float* base_b   = (const float*)d_in[6];
    const float* bias     = (const float*)d_in[7];
    float* out = (float*)d_out;

    char* ws = (char*)d_ws;
    const size_t CUR_OFF  = 0;             //      4,096 B (512 cursors, padded)
    const size_t WP_OFF   = 4096;          //    294,912 B
    const size_t DIS_OFF  = 299008;        //     65,536 B
    const size_t DEG_OFF  = 364544;        //     65,536 B
    const size_t DADJ_OFF = 430080;        //  8,388,608 B (16384 x 256 ushort)
    const size_t ES_OFF   = 8818688;       // max(ebuf 5,767,168 ; Ssc 4,194,304)
    const size_t NEEDED   = 14585856;
    if (ws_size < NEEDED) return;

    int*    cursor = (int*)(ws + CUR_OFF);
    ushort* Wp     = (ushort*)(ws + WP_OFF);
    float*  dis    = (float*)(ws + DIS_OFF);
    int*    degarr = (int*)(ws + DEG_OFF);
    ushort* dadj   = (ushort*)(ws + DADJ_OFF);
    uint32* ebuf   = (uint32*)(ws + ES_OFF);       // dead after degb_kernel
    ushort* Ssc    = (ushort*)(ws + ES_OFF);       // written by support afterwards

    transw_kernel<<<576, 256, 0, stream>>>(spline_w, base_w, Wp, cursor);
    sort_kernel<<<512, 256, 0, stream>>>(ei, cursor, ebuf);
    degb_kernel<<<NBUCK, 256, 0, stream>>>(cursor, ebuf, dis, degarr, dadj);
    support_kernel<<<N_NODES / 16, 256, 0, stream>>>(x, ln_gamma, ln_beta, Wp,
                                                     base_b, dis, Ssc);
    aggregate_kernel<<<N_NODES, 128, 0, stream>>>(degarr, dadj, Ssc, dis, bias, out);
}

// Round 7
// 85.255 us; speedup vs baseline: 1.1039x; 1.0579x over previous
//
#include <hip/hip_runtime.h>

#define N_NODES 16384
#define NE 524288
#define KDIM 1152          // IN*NG + IN
#define KSTEPS 36          // 1152 / 32
#define NBUCK 512          // buckets of 32 nodes
#define SBLK 512           // sort blocks; each owns 1024 edges = 2048 entries
#define SPB 2048           // directed entries per sort block (exact)
#define MROW 516           // padded LDS row stride (words) to break bank conflicts
#define DCAP 256           // per-node dedup'd neighbor capacity (mean 64)

typedef unsigned int uint32;
typedef unsigned short ushort;
typedef __attribute__((ext_vector_type(8))) short bf16x8;
typedef __attribute__((ext_vector_type(4))) float f32x4;

__device__ __forceinline__ ushort f2bf(float f) {
    unsigned u = __float_as_uint(f);
    unsigned r = (u + 0x7fffu + ((u >> 16) & 1u)) >> 16;
    return (ushort)r;
}
__device__ __forceinline__ float bflo(uint32 u) {
    return __uint_as_float(u << 16);
}
__device__ __forceinline__ float bfhi(uint32 u) {
    return __uint_as_float(u & 0xffff0000u);
}

// ---------------- weight pack into MFMA B-fragment order (bf16) ----------------
__global__ __launch_bounds__(256) void transw_kernel(
    const float* __restrict__ sw, const float* __restrict__ bw,
    ushort* __restrict__ Wp) {
    int idx = blockIdx.x * 256 + threadIdx.x;      // 0 .. 147455
    int i  = idx & 7;
    int l  = (idx >> 3) & 63;
    int ct = (idx >> 9) & 7;
    int kk = idx >> 12;
    int k   = kk * 32 + ((l >> 4) << 3) + i;
    int col = ct * 16 + (l & 15);
    float v = (k < 1024) ? sw[col * 1024 + k] : bw[col * 128 + (k - 1024)];
    Wp[idx] = f2bf(v);
}

// ---------------- in-LDS bucket sort; ALL global writes coalesced ----------------
// 512 blocks x 256 threads; block b emits ebuf[b][0..2048) grouped by bucket,
// plus ocnt[b][q] = off | (cnt<<16) per bucket.
__global__ __launch_bounds__(256) void sort_kernel(
    const int* __restrict__ ei, uint32* __restrict__ ebuf,
    uint32* __restrict__ ocnt) {
    __shared__ int hcnt[NBUCK];
    __shared__ int lbase[NBUCK];
    __shared__ uint32 st[SPB];                     // 8 KB
    const int t = threadIdx.x;
    hcnt[t] = 0;
    hcnt[t + 256] = 0;
    __syncthreads();

    int bk[8], sl[8];
    uint32 pk[8];
#pragma unroll
    for (int k = 0; k < 4; ++k) {
        int e = blockIdx.x * 1024 + k * 256 + t;
        int a = ei[e];
        int b = ei[NE + e];
        bk[2 * k]     = a >> 5;
        pk[2 * k]     = ((uint32)(a & 31) << 14) | (uint32)b;
        bk[2 * k + 1] = b >> 5;
        pk[2 * k + 1] = ((uint32)(b & 31) << 14) | (uint32)a;
        sl[2 * k]     = atomicAdd(&hcnt[bk[2 * k]], 1);
        sl[2 * k + 1] = atomicAdd(&hcnt[bk[2 * k + 1]], 1);
    }
    __syncthreads();

    // inclusive Hillis-Steele scan over 512 counts (2 elems/thread)
    const int c0 = hcnt[t];
    const int c1 = hcnt[t + 256];
    for (int off = 1; off < NBUCK; off <<= 1) {
        int v0 = hcnt[t], v1 = hcnt[t + 256];
        int a0 = (t >= off) ? hcnt[t - off] : 0;
        int a1 = hcnt[t + 256 - off];
        __syncthreads();
        hcnt[t] = v0 + a0;
        hcnt[t + 256] = v1 + a1;
        __syncthreads();
    }
    const int e0 = hcnt[t] - c0;                   // exclusive base, bucket t
    const int e1 = hcnt[t + 256] - c1;             // exclusive base, bucket t+256
    lbase[t] = e0;
    lbase[t + 256] = e1;
    uint32* oc = ocnt + (size_t)blockIdx.x * NBUCK;
    oc[t]       = (uint32)e0 | ((uint32)c0 << 16);
    oc[t + 256] = (uint32)e1 | ((uint32)c1 << 16);
    __syncthreads();

    // place entries grouped by bucket in LDS, then coalesced flush
#pragma unroll
    for (int k = 0; k < 8; ++k) st[lbase[bk[k]] + sl[k]] = pk[k];
    __syncthreads();
    uint32* gout = ebuf + (size_t)blockIdx.x * SPB;
#pragma unroll
    for (int k = 0; k < 8; ++k) gout[t + k * 256] = st[t + k * 256];
}

// ---------------- per-bucket LDS bitmask -> dedup'd CSR (deg, dis, dadj) ----------------
// 512 blocks (one per 32-node bucket) x 256 threads (4 waves x 8 nodes each)
__global__ __launch_bounds__(256) void degb_kernel(
    const uint32* __restrict__ ebuf, const uint32* __restrict__ ocnt,
    float* __restrict__ dis, int* __restrict__ degarr,
    ushort* __restrict__ dadj) {
    __shared__ uint32 mask[32 * MROW];              // 66,048 B
    const int t = threadIdx.x;
    const int bkt = blockIdx.x;
    for (int i = t; i < 32 * MROW; i += 256) mask[i] = 0;
    __syncthreads();

    // gather this bucket's runs from all 512 sort-block regions
    for (int b = t; b < SBLK; b += 256) {
        uint32 oc = ocnt[(size_t)b * NBUCK + bkt];
        int off = (int)(oc & 0xFFFFu);
        int cn  = (int)(oc >> 16);
        const uint32* p = ebuf + (size_t)b * SPB + off;
        for (int s = 0; s < cn; ++s) {
            uint32 e = p[s];
            atomicOr(&mask[(e >> 14) * MROW + ((e & 16383) >> 5)],
                     1u << (e & 31));
        }
    }
    __syncthreads();

    // compaction: wave w handles nodes w*8 .. w*8+7; lane owns words lane+64j
    const int lane = t & 63;
    const int w = t >> 6;
    for (int n = w * 8; n < w * 8 + 8; ++n) {
        const uint32* row = &mask[n * MROW];
        uint32 wd[8];
        int c = 0;
#pragma unroll
        for (int j = 0; j < 8; ++j) {
            wd[j] = row[lane + 64 * j];
            c += __popc(wd[j]);
        }
        int inc = c;
#pragma unroll
        for (int o = 1; o < 64; o <<= 1) {
            int v = __shfl_up(inc, o);
            if (lane >= o) inc += v;
        }
        int total = __shfl(inc, 63);
        int pos = inc - c;                          // exclusive base for this lane
        const int node = bkt * 32 + n;
        if (lane == 0) {
            dis[node] = rsqrtf((float)total);
            degarr[node] = total > DCAP ? DCAP : total;
        }
        ushort* drow = dadj + (size_t)node * DCAP;
#pragma unroll
        for (int j = 0; j < 8; ++j) {
            uint32 bits = wd[j];
            int base = (lane + 64 * j) * 32;
            while (bits) {
                int b = __ffs(bits) - 1;
                bits &= bits - 1;
                if (pos < DCAP) drow[pos] = (ushort)(base + b);
                ++pos;
            }
        }
    }
}

// ---------------- fused FastKAN support (bf16 MFMA), pre-scaled by dis ----------------
__global__ __launch_bounds__(256) void support_kernel(
    const float* __restrict__ x, const float* __restrict__ gamma,
    const float* __restrict__ beta, const ushort* __restrict__ Wp,
    const float* __restrict__ base_b, const float* __restrict__ dis,
    ushort* __restrict__ Ssc) {
    __shared__ ushort Bs[16][KDIM];                 // 36864 B
    const int t = threadIdx.x;
    const int lane = t & 63;
    const int w = t >> 6;
    const int nodeBase = blockIdx.x * 16;

    const float g0 = gamma[lane], g1 = gamma[lane + 64];
    const float be0 = beta[lane], be1 = beta[lane + 64];

    for (int n = w * 4; n < w * 4 + 4; ++n) {
        const int row = nodeBase + n;
        float f0 = x[(size_t)row * 128 + lane];
        float f1 = x[(size_t)row * 128 + lane + 64];
        float s = f0 + f1;
#pragma unroll
        for (int o = 32; o; o >>= 1) s += __shfl_xor(s, o);
        float mu = s * 0.0078125f;
        float d0 = f0 - mu, d1 = f1 - mu;
        float v = d0 * d0 + d1 * d1;
#pragma unroll
        for (int o = 32; o; o >>= 1) v += __shfl_xor(v, o);
        float rstd = rsqrtf(v * 0.0078125f + 1e-5f);
        float h0 = d0 * rstd * g0 + be0;
        float h1 = d1 * rstd * g1 + be1;
        ushort pk0[8] __attribute__((aligned(16)));
        ushort pk1[8] __attribute__((aligned(16)));
#pragma unroll
        for (int g = 0; g < 8; ++g) {
            float gv = -2.0f + (float)g * (4.0f / 7.0f);
            float z0 = (h0 - gv) * 1.75f;
            float z1 = (h1 - gv) * 1.75f;
            pk0[g] = f2bf(__expf(-z0 * z0));
            pk1[g] = f2bf(__expf(-z1 * z1));
        }
        *reinterpret_cast<uint4*>(&Bs[n][lane * 8]) =
            *reinterpret_cast<const uint4*>(pk0);
        *reinterpret_cast<uint4*>(&Bs[n][(lane + 64) * 8]) =
            *reinterpret_cast<const uint4*>(pk1);
        Bs[n][1024 + lane]      = f2bf(f0 / (1.0f + __expf(-f0)));
        Bs[n][1024 + lane + 64] = f2bf(f1 / (1.0f + __expf(-f1)));
    }
    __syncthreads();

    const int ct0 = w * 2;
    f32x4 acc0 = {0.f, 0.f, 0.f, 0.f};
    f32x4 acc1 = {0.f, 0.f, 0.f, 0.f};
    const ushort* ArowBase = &Bs[lane & 15][(lane >> 4) * 8];
    const bf16x8* Wv = (const bf16x8*)Wp;
#pragma unroll 4
    for (int kk = 0; kk < KSTEPS; ++kk) {
        bf16x8 a = *reinterpret_cast<const bf16x8*>(ArowBase + kk * 32);
        bf16x8 b0 = Wv[(size_t)(kk * 8 + ct0) * 64 + lane];
        bf16x8 b1 = Wv[(size_t)(kk * 8 + ct0 + 1) * 64 + lane];
        acc0 = __builtin_amdgcn_mfma_f32_16x16x32_bf16(a, b0, acc0, 0, 0, 0);
        acc1 = __builtin_amdgcn_mfma_f32_16x16x32_bf16(a, b1, acc1, 0, 0, 0);
    }

    const int col0 = ct0 * 16 + (lane & 15);
    const int rbase = (lane >> 4) * 4;
    const float bb0 = base_b[col0];
    const float bb1 = base_b[col0 + 16];
#pragma unroll
    for (int r = 0; r < 4; ++r) {
        const int row = nodeBase + rbase + r;
        const float di = dis[row];
        Ssc[(size_t)row * 128 + col0]      = f2bf((acc0[r] + bb0) * di);
        Ssc[(size_t)row * 128 + col0 + 16] = f2bf((acc1[r] + bb1) * di);
    }
}

// ---------------- aggregation from dedup'd CSR ----------------
__global__ __launch_bounds__(128) void aggregate_kernel(
    const int* __restrict__ degarr, const ushort* __restrict__ dadj,
    const ushort* __restrict__ Ssc, const float* __restrict__ dis,
    const float* __restrict__ bias, float* __restrict__ out) {
    __shared__ ushort lst[DCAP];
    __shared__ float part[2][128];
    const int t = threadIdx.x;
    const int i = blockIdx.x;

    const int total = degarr[i];
    const ushort* drow = dadj + (size_t)i * DCAP;
    if (t < total) lst[t] = drow[t];
    if (t + 128 < total) lst[t + 128] = drow[t + 128];
    __syncthreads();

    const int lane = t & 63;
    const int wv = t >> 6;
    const uint32* S32 = (const uint32*)Ssc;          // row stride 64 uints
    float a0 = 0.f, a1 = 0.f;
    int idx = wv;
    for (; idx + 6 < total; idx += 8) {
        int j0 = lst[idx], j1 = lst[idx + 2], j2 = lst[idx + 4], j3 = lst[idx + 6];
        uint32 u0 = S32[(size_t)j0 * 64 + lane];
        uint32 u1 = S32[(size_t)j1 * 64 + lane];
        uint32 u2 = S32[(size_t)j2 * 64 + lane];
        uint32 u3 = S32[(size_t)j3 * 64 + lane];
        a0 += (bflo(u0) + bflo(u1)) + (bflo(u2) + bflo(u3));
        a1 += (bfhi(u0) + bfhi(u1)) + (bfhi(u2) + bfhi(u3));
    }
    for (; idx < total; idx += 2) {
        uint32 u = S32[(size_t)lst[idx] * 64 + lane];
        a0 += bflo(u);
        a1 += bfhi(u);
    }
    part[wv][lane * 2]     = a0;
    part[wv][lane * 2 + 1] = a1;
    __syncthreads();

    float v = part[0][t] + part[1][t];
    out[(size_t)i * 128 + t] = v * dis[i] + bias[t];
}

extern "C" void kernel_launch(void* const* d_in, const int* in_sizes, int n_in,
                              void* d_out, int out_size, void* d_ws, size_t ws_size,
                              hipStream_t stream) {
    const float* x        = (const float*)d_in[0];
    const int*   ei       = (const int*)d_in[1];
    const float* ln_gamma = (const float*)d_in[2];
    const float* ln_beta  = (const float*)d_in[3];
    const float* spline_w = (const float*)d_in[4];
    const float* base_w   = (const float*)d_in[5];
    const float* base_b   = (const float*)d_in[6];
    const float* bias     = (const float*)d_in[7];
    float* out = (float*)d_out;

    char* ws = (char*)d_ws;
    const size_t WP_OFF   = 0;             //    294,912 B
    const size_t DIS_OFF  = 294912;        //     65,536 B
    const size_t DEG_OFF  = 360448;        //     65,536 B
    const size_t DADJ_OFF = 425984;        //  8,388,608 B (16384 x 256 ushort)
    const size_t ES_OFF   = 8814592;       // ebuf 4 MB + ocnt 1 MB (alias Ssc 4 MB)
    const size_t OCNT_OFF = ES_OFF + (size_t)SBLK * SPB * 4;
    const size_t NEEDED   = ES_OFF + 5242880;
    if (ws_size < NEEDED) return;

    ushort* Wp     = (ushort*)(ws + WP_OFF);
    float*  dis    = (float*)(ws + DIS_OFF);
    int*    degarr = (int*)(ws + DEG_OFF);
    ushort* dadj   = (ushort*)(ws + DADJ_OFF);
    uint32* ebuf   = (uint32*)(ws + ES_OFF);       // dead after degb_kernel
    uint32* ocnt   = (uint32*)(ws + OCNT_OFF);     // dead after degb_kernel
    ushort* Ssc    = (ushort*)(ws + ES_OFF);       // aliases ebuf afterwards

    transw_kernel<<<576, 256, 0, stream>>>(spline_w, base_w, Wp);
    sort_kernel<<<SBLK, 256, 0, stream>>>(ei, ebuf, ocnt);
    degb_kernel<<<NBUCK, 256, 0, stream>>>(ebuf, ocnt, dis, degarr, dadj);
    support_kernel<<<N_NODES / 16, 256, 0, stream>>>(x, ln_gamma, ln_beta, Wp,
                                                     base_b, dis, Ssc);
    aggregate_kernel<<<N_NODES, 128, 0, stream>>>(degarr, dadj, Ssc, dis, bias, out);
}

// Round 8
// 78.157 us; speedup vs baseline: 1.2041x; 1.0908x over previous
//
#include <hip/hip_runtime.h>

#define N_NODES 16384
#define NE 524288
#define KDIM 1152          // IN*NG + IN
#define KPAD 1160          // padded LDS row (ushorts): stride 2320 B breaks banks
#define KSTEPS 36          // 1152 / 32
#define NBUCK 512          // buckets of 32 nodes
#define SBLK 512           // sort blocks; each owns 1024 edges = 2048 entries
#define SPB 2048           // directed entries per sort block (exact)
#define MROW 516           // padded LDS row stride (words) for degb bitmask
#define DCAP 256           // per-node dedup'd neighbor capacity (mean 64)

typedef unsigned int uint32;
typedef unsigned short ushort;
typedef __attribute__((ext_vector_type(8))) short bf16x8;
typedef __attribute__((ext_vector_type(4))) float f32x4;

__device__ __forceinline__ ushort f2bf(float f) {
    unsigned u = __float_as_uint(f);
    unsigned r = (u + 0x7fffu + ((u >> 16) & 1u)) >> 16;
    return (ushort)r;
}
__device__ __forceinline__ float bflo(uint32 u) {
    return __uint_as_float(u << 16);
}
__device__ __forceinline__ float bfhi(uint32 u) {
    return __uint_as_float(u & 0xffff0000u);
}

// ================= launch A: sort (blocks 0..511) + weight pack (512..1087) =================
__global__ __launch_bounds__(256) void pre_kernel(
    const int* __restrict__ ei, uint32* __restrict__ ebuf,
    uint32* __restrict__ ocnt, const float* __restrict__ sw,
    const float* __restrict__ bw, ushort* __restrict__ Wp) {
    const int t = threadIdx.x;
    if (blockIdx.x >= SBLK) {
        // ---- transw: Wp[((kk*8+ct)*64+lane)*8+i] = bf16(W[k][col]) ----
        int idx = (blockIdx.x - SBLK) * 256 + t;   // 0 .. 147455
        int i  = idx & 7;
        int l  = (idx >> 3) & 63;
        int ct = (idx >> 9) & 7;
        int kk = idx >> 12;
        int k   = kk * 32 + ((l >> 4) << 3) + i;
        int col = ct * 16 + (l & 15);
        float v = (k < 1024) ? sw[col * 1024 + k] : bw[col * 128 + (k - 1024)];
        Wp[idx] = f2bf(v);
        return;
    }
    // ---- in-LDS bucket sort; all global writes coalesced ----
    __shared__ int hcnt[NBUCK];
    __shared__ int lbase[NBUCK];
    __shared__ uint32 st[SPB];                     // 8 KB
    hcnt[t] = 0;
    hcnt[t + 256] = 0;
    __syncthreads();

    int bk[8], sl[8];
    uint32 pk[8];
#pragma unroll
    for (int k = 0; k < 4; ++k) {
        int e = blockIdx.x * 1024 + k * 256 + t;
        int a = ei[e];
        int b = ei[NE + e];
        bk[2 * k]     = a >> 5;
        pk[2 * k]     = ((uint32)(a & 31) << 14) | (uint32)b;
        bk[2 * k + 1] = b >> 5;
        pk[2 * k + 1] = ((uint32)(b & 31) << 14) | (uint32)a;
        sl[2 * k]     = atomicAdd(&hcnt[bk[2 * k]], 1);
        sl[2 * k + 1] = atomicAdd(&hcnt[bk[2 * k + 1]], 1);
    }
    __syncthreads();

    const int c0 = hcnt[t];
    const int c1 = hcnt[t + 256];
    for (int off = 1; off < NBUCK; off <<= 1) {
        int v0 = hcnt[t], v1 = hcnt[t + 256];
        int a0 = (t >= off) ? hcnt[t - off] : 0;
        int a1 = hcnt[t + 256 - off];
        __syncthreads();
        hcnt[t] = v0 + a0;
        hcnt[t + 256] = v1 + a1;
        __syncthreads();
    }
    const int e0 = hcnt[t] - c0;
    const int e1 = hcnt[t + 256] - c1;
    lbase[t] = e0;
    lbase[t + 256] = e1;
    uint32* oc = ocnt + (size_t)blockIdx.x * NBUCK;
    oc[t]       = (uint32)e0 | ((uint32)c0 << 16);
    oc[t + 256] = (uint32)e1 | ((uint32)c1 << 16);
    __syncthreads();

#pragma unroll
    for (int k = 0; k < 8; ++k) st[lbase[bk[k]] + sl[k]] = pk[k];
    __syncthreads();
    uint32* gout = ebuf + (size_t)blockIdx.x * SPB;
#pragma unroll
    for (int k = 0; k < 8; ++k) gout[t + k * 256] = st[t + k * 256];
}

// ========== launch B: degb (blocks 0..511) + support (blocks 512..1023) ==========
// shared LDS arena: max(degb 66,048 B ; support 32*KPAD*2 = 74,240 B)
__global__ __launch_bounds__(256) void mid_kernel(
    const uint32* __restrict__ ebuf, const uint32* __restrict__ ocnt,
    float* __restrict__ dis, int* __restrict__ degarr,
    ushort* __restrict__ dadj, const float* __restrict__ x,
    const float* __restrict__ gamma, const float* __restrict__ beta,
    const ushort* __restrict__ Wp, const float* __restrict__ base_b,
    ushort* __restrict__ S) {
    __shared__ __align__(16) uint32 smemw[18560];   // 74,240 B
    const int t = threadIdx.x;
    const int lane = t & 63;
    const int w = t >> 6;

    if (blockIdx.x < NBUCK) {
        // ---- degb: per-bucket bitmask -> dedup'd CSR ----
        uint32* mask = smemw;                       // [32][MROW]
        const int bkt = blockIdx.x;
        for (int i = t; i < 32 * MROW; i += 256) mask[i] = 0;
        __syncthreads();

        for (int b = t; b < SBLK; b += 256) {
            uint32 oc = ocnt[(size_t)b * NBUCK + bkt];
            int off = (int)(oc & 0xFFFFu);
            int cn  = (int)(oc >> 16);
            const uint32* p = ebuf + (size_t)b * SPB + off;
            for (int s = 0; s < cn; ++s) {
                uint32 e = p[s];
                atomicOr(&mask[(e >> 14) * MROW + ((e & 16383) >> 5)],
                         1u << (e & 31));
            }
        }
        __syncthreads();

        for (int n = w * 8; n < w * 8 + 8; ++n) {
            const uint32* row = &mask[n * MROW];
            uint32 wd[8];
            int c = 0;
#pragma unroll
            for (int j = 0; j < 8; ++j) {
                wd[j] = row[lane + 64 * j];
                c += __popc(wd[j]);
            }
            int inc = c;
#pragma unroll
            for (int o = 1; o < 64; o <<= 1) {
                int v = __shfl_up(inc, o);
                if (lane >= o) inc += v;
            }
            int total = __shfl(inc, 63);
            int pos = inc - c;
            const int node = bkt * 32 + n;
            if (lane == 0) {
                dis[node] = rsqrtf((float)total);
                degarr[node] = total > DCAP ? DCAP : total;
            }
            ushort* drow = dadj + (size_t)node * DCAP;
#pragma unroll
            for (int j = 0; j < 8; ++j) {
                uint32 bits = wd[j];
                int base = (lane + 64 * j) * 32;
                while (bits) {
                    int b = __ffs(bits) - 1;
                    bits &= bits - 1;
                    if (pos < DCAP) drow[pos] = (ushort)(base + b);
                    ++pos;
                }
            }
        }
        return;
    }

    // ---- support: 32 nodes/block, FastKAN basis + bf16 MFMA (unscaled S) ----
    ushort* Bs = (ushort*)smemw;                    // [32][KPAD]
    const int nodeBase = (blockIdx.x - NBUCK) * 32;

    const float g0 = gamma[lane], g1 = gamma[lane + 64];
    const float be0 = beta[lane], be1 = beta[lane + 64];

    for (int n = w * 8; n < w * 8 + 8; ++n) {
        const int row = nodeBase + n;
        float f0 = x[(size_t)row * 128 + lane];
        float f1 = x[(size_t)row * 128 + lane + 64];
        float s = f0 + f1;
#pragma unroll
        for (int o = 32; o; o >>= 1) s += __shfl_xor(s, o);
        float mu = s * 0.0078125f;
        float d0 = f0 - mu, d1 = f1 - mu;
        float v = d0 * d0 + d1 * d1;
#pragma unroll
        for (int o = 32; o; o >>= 1) v += __shfl_xor(v, o);
        float rstd = rsqrtf(v * 0.0078125f + 1e-5f);
        float h0 = d0 * rstd * g0 + be0;
        float h1 = d1 * rstd * g1 + be1;
        ushort pk0[8] __attribute__((aligned(16)));
        ushort pk1[8] __attribute__((aligned(16)));
#pragma unroll
        for (int g = 0; g < 8; ++g) {
            float gv = -2.0f + (float)g * (4.0f / 7.0f);
            float z0 = (h0 - gv) * 1.75f;
            float z1 = (h1 - gv) * 1.75f;
            pk0[g] = f2bf(__expf(-z0 * z0));
            pk1[g] = f2bf(__expf(-z1 * z1));
        }
        *reinterpret_cast<uint4*>(&Bs[n * KPAD + lane * 8]) =
            *reinterpret_cast<const uint4*>(pk0);
        *reinterpret_cast<uint4*>(&Bs[n * KPAD + (lane + 64) * 8]) =
            *reinterpret_cast<const uint4*>(pk1);
        Bs[n * KPAD + 1024 + lane]      = f2bf(f0 / (1.0f + __expf(-f0)));
        Bs[n * KPAD + 1024 + lane + 64] = f2bf(f1 / (1.0f + __expf(-f1)));
    }
    __syncthreads();

    // wave w -> col-tiles {2w, 2w+1}, row-halves lo (0..15) / hi (16..31)
    const int ct0 = w * 2;
    f32x4 accA = {0.f, 0.f, 0.f, 0.f};             // lo, ct0
    f32x4 accB = {0.f, 0.f, 0.f, 0.f};             // lo, ct1
    f32x4 accC = {0.f, 0.f, 0.f, 0.f};             // hi, ct0
    f32x4 accD = {0.f, 0.f, 0.f, 0.f};             // hi, ct1
    const ushort* Alo = &Bs[(lane & 15) * KPAD + (lane >> 4) * 8];
    const ushort* Ahi = Alo + 16 * KPAD;
    const bf16x8* Wv = (const bf16x8*)Wp;
#pragma unroll 4
    for (int kk = 0; kk < KSTEPS; ++kk) {
        bf16x8 alo = *reinterpret_cast<const bf16x8*>(Alo + kk * 32);
        bf16x8 ahi = *reinterpret_cast<const bf16x8*>(Ahi + kk * 32);
        bf16x8 b0 = Wv[(size_t)(kk * 8 + ct0) * 64 + lane];
        bf16x8 b1 = Wv[(size_t)(kk * 8 + ct0 + 1) * 64 + lane];
        accA = __builtin_amdgcn_mfma_f32_16x16x32_bf16(alo, b0, accA, 0, 0, 0);
        accB = __builtin_amdgcn_mfma_f32_16x16x32_bf16(alo, b1, accB, 0, 0, 0);
        accC = __builtin_amdgcn_mfma_f32_16x16x32_bf16(ahi, b0, accC, 0, 0, 0);
        accD = __builtin_amdgcn_mfma_f32_16x16x32_bf16(ahi, b1, accD, 0, 0, 0);
    }

    const int col0 = ct0 * 16 + (lane & 15);
    const int rbase = (lane >> 4) * 4;
    const float bb0 = base_b[col0];
    const float bb1 = base_b[col0 + 16];
#pragma unroll
    for (int r = 0; r < 4; ++r) {
        const int rlo = nodeBase + rbase + r;
        const int rhi = rlo + 16;
        S[(size_t)rlo * 128 + col0]      = f2bf(accA[r] + bb0);
        S[(size_t)rlo * 128 + col0 + 16] = f2bf(accB[r] + bb1);
        S[(size_t)rhi * 128 + col0]      = f2bf(accC[r] + bb0);
        S[(size_t)rhi * 128 + col0 + 16] = f2bf(accD[r] + bb1);
    }
}

// ========== launch C: aggregation, out[i] = dis_i * sum_j dis_j*S_j + bias ==========
// 2 nodes per block; 128 threads per node
__global__ __launch_bounds__(256) void aggregate_kernel(
    const int* __restrict__ degarr, const ushort* __restrict__ dadj,
    const ushort* __restrict__ S, const float* __restrict__ dis,
    const float* __restrict__ bias, float* __restrict__ out) {
    __shared__ ushort lst[2][DCAP];
    __shared__ float part[2][2][128];
    const int t = threadIdx.x;
    const int g = t >> 7;
    const int tl = t & 127;
    const int i = blockIdx.x * 2 + g;

    const int total = degarr[i];
    const ushort* drow = dadj + (size_t)i * DCAP;
    if (tl < total) lst[g][tl] = drow[tl];
    if (tl + 128 < total) lst[g][tl + 128] = drow[tl + 128];
    __syncthreads();

    const int lane = t & 63;
    const int wv = (t >> 6) & 1;
    const uint32* S32 = (const uint32*)S;            // row stride 64 uints
    float a0 = 0.f, a1 = 0.f;
    int idx = wv;
    for (; idx + 6 < total; idx += 8) {
        int j0 = lst[g][idx], j1 = lst[g][idx + 2];
        int j2 = lst[g][idx + 4], j3 = lst[g][idx + 6];
        float d0 = dis[j0], d1 = dis[j1], d2 = dis[j2], d3 = dis[j3];
        uint32 u0 = S32[(size_t)j0 * 64 + lane];
        uint32 u1 = S32[(size_t)j1 * 64 + lane];
        uint32 u2 = S32[(size_t)j2 * 64 + lane];
        uint32 u3 = S32[(size_t)j3 * 64 + lane];
        a0 += (d0 * bflo(u0) + d1 * bflo(u1)) + (d2 * bflo(u2) + d3 * bflo(u3));
        a1 += (d0 * bfhi(u0) + d1 * bfhi(u1)) + (d2 * bfhi(u2) + d3 * bfhi(u3));
    }
    for (; idx < total; idx += 2) {
        int j = lst[g][idx];
        float d = dis[j];
        uint32 u = S32[(size_t)j * 64 + lane];
        a0 += d * bflo(u);
        a1 += d * bfhi(u);
    }
    part[g][wv][lane * 2]     = a0;
    part[g][wv][lane * 2 + 1] = a1;
    __syncthreads();

    float v = part[g][0][tl] + part[g][1][tl];
    out[(size_t)i * 128 + tl] = v * dis[i] + bias[tl];
}

extern "C" void kernel_launch(void* const* d_in, const int* in_sizes, int n_in,
                              void* d_out, int out_size, void* d_ws, size_t ws_size,
                              hipStream_t stream) {
    const float* x        = (const float*)d_in[0];
    const int*   ei       = (const int*)d_in[1];
    const float* ln_gamma = (const float*)d_in[2];
    const float* ln_beta  = (const float*)d_in[3];
    const float* spline_w = (const float*)d_in[4];
    const float* base_w   = (const float*)d_in[5];
    const float* base_b   = (const float*)d_in[6];
    const float* bias     = (const float*)d_in[7];
    float* out = (float*)d_out;

    char* ws = (char*)d_ws;
    const size_t WP_OFF   = 0;             //    294,912 B
    const size_t DIS_OFF  = 294912;        //     65,536 B
    const size_t DEG_OFF  = 360448;        //     65,536 B
    const size_t DADJ_OFF = 425984;        //  8,388,608 B
    const size_t EBUF_OFF = 8814592;       //  4,194,304 B
    const size_t OCNT_OFF = 13008896;      //  1,048,576 B
    const size_t S_OFF    = 14057472;      //  4,194,304 B
    const size_t NEEDED   = 18251776;
    if (ws_size < NEEDED) return;

    ushort* Wp     = (ushort*)(ws + WP_OFF);
    float*  dis    = (float*)(ws + DIS_OFF);
    int*    degarr = (int*)(ws + DEG_OFF);
    ushort* dadj   = (ushort*)(ws + DADJ_OFF);
    uint32* ebuf   = (uint32*)(ws + EBUF_OFF);
    uint32* ocnt   = (uint32*)(ws + OCNT_OFF);
    ushort* S      = (ushort*)(ws + S_OFF);

    pre_kernel<<<SBLK + 576, 256, 0, stream>>>(ei, ebuf, ocnt,
                                               spline_w, base_w, Wp);
    mid_kernel<<<NBUCK + N_NODES / 32, 256, 0, stream>>>(
        ebuf, ocnt, dis, degarr, dadj, x, ln_gamma, ln_beta, Wp, base_b, S);
    aggregate_kernel<<<N_NODES / 2, 256, 0, stream>>>(degarr, dadj, S, dis,
                                                      bias, out);
}